// Round 1
// baseline (1874.074 us; speedup 1.0000x reference)
//
#include <hip/hip_runtime.h>
#include <math.h>
#include <stddef.h>

#define N_NODES 16384
#define F_DIM   500
#define E_DIM   128
#define LIN_DIM 128
#define C_DIM   10
#define B_DIM   4096

// ---------------------------------------------------------------------------
// K0: small transpose  dst[c*R + r] = src[r*C + c]   (src is [R][C])
// ---------------------------------------------------------------------------
__global__ void k_transpose(const float* __restrict__ src, float* __restrict__ dst,
                            int R, int C) {
    int idx = blockIdx.x * blockDim.x + threadIdx.x;
    if (idx < R * C) {
        int r = idx / C, c = idx % C;
        dst[c * R + r] = src[idx];
    }
}

// ---------------------------------------------------------------------------
// K1: layer-1 aggregation. One block per node: scan adj row (float4), collect
// nonzero column indices in LDS, then register-accumulate data rows.
// neigh1[i][f] = sum_{j in nbr(i)} data[j][f] / deg(i)
// ---------------------------------------------------------------------------
__global__ __launch_bounds__(256) void k_agg1(const float* __restrict__ adj,
                                              const float* __restrict__ data,
                                              float* __restrict__ neigh1) {
    const int i = blockIdx.x;
    const float* row = adj + (size_t)i * N_NODES;
    __shared__ int s_cnt;
    __shared__ int s_idx[256];
    if (threadIdx.x == 0) s_cnt = 0;
    __syncthreads();
    // 16384 floats / (256 thr * 4) = 16 passes
    for (int base = 0; base < N_NODES; base += 1024) {
        float4 v = ((const float4*)(row + base))[threadIdx.x];
        int col = base + threadIdx.x * 4;
        if (v.x != 0.0f) { int p = atomicAdd(&s_cnt, 1); if (p < 256) s_idx[p] = col;     }
        if (v.y != 0.0f) { int p = atomicAdd(&s_cnt, 1); if (p < 256) s_idx[p] = col + 1; }
        if (v.z != 0.0f) { int p = atomicAdd(&s_cnt, 1); if (p < 256) s_idx[p] = col + 2; }
        if (v.w != 0.0f) { int p = atomicAdd(&s_cnt, 1); if (p < 256) s_idx[p] = col + 3; }
    }
    __syncthreads();
    const int cnt = s_cnt;                 // deg >= 1 (self-loop)
    const float inv = 1.0f / (float)cnt;
    const int t = threadIdx.x;
    float acc0 = 0.0f, acc1 = 0.0f;
    for (int k = 0; k < cnt; ++k) {
        const float* drow = data + (size_t)s_idx[k] * F_DIM;
        acc0 += drow[t];
        if (t + 256 < F_DIM) acc1 += drow[t + 256];
    }
    float* orow = neigh1 + (size_t)i * F_DIM;
    orow[t] = acc0 * inv;
    if (t + 256 < F_DIM) orow[t + 256] = acc1 * inv;
}

// ---------------------------------------------------------------------------
// K2: fp32 tiled GEMM.  C[M][128] = A[M][Ktot] @ Bt[Ktot][128] + bias
// A(i,k) = (k < KA) ? Aa[i*KA + k] : Ab[i*(Ktot-KA) + (k-KA)]   (concat)
// Tile: 32 rows x 128 cols, K chunk 32. 256 threads, 4x4 micro-tile each.
// ---------------------------------------------------------------------------
#define GM 32
#define GK 32
__global__ __launch_bounds__(256) void k_gemm(const float* __restrict__ Aa, int KA,
                                              const float* __restrict__ Ab, int Ktot,
                                              const float* __restrict__ Bt,
                                              const float* __restrict__ bias,
                                              float* __restrict__ Cout, int M) {
    __shared__ float sAT[GK][GM + 4];   // [kk][m], pad -> row stride 36 (16B multiple)
    __shared__ float sW[GK][128];
    const int tid = threadIdx.x;
    const int m0 = (tid & 7) * 4;        // 8 groups of 4 rows
    const int e0 = (tid >> 3) * 4;       // 32 groups of 4 cols
    const int blockM = blockIdx.x * GM;
    const int KB = Ktot - KA;
    float acc[4][4] = {};

    for (int k0 = 0; k0 < Ktot; k0 += GK) {
        // stage A tile transposed: sAT[kk][m]
        {
            int kk = tid & (GK - 1);
            int mm = tid >> 5;           // 0..7
#pragma unroll
            for (int r = 0; r < 4; ++r) {
                int m = mm + r * 8;
                int node = blockM + m;
                int k = k0 + kk;
                float v = 0.0f;
                if (k < Ktot) {
                    v = (k < KA) ? Aa[(size_t)node * KA + k]
                                 : Ab[(size_t)node * KB + (k - KA)];
                }
                sAT[kk][m] = v;
            }
        }
        // stage W tile: sW[kk][e], 32*128 = 4096 elems, 16/thread
#pragma unroll
        for (int r = 0; r < 16; ++r) {
            int idx = tid + 256 * r;
            int kk = idx >> 7, e = idx & 127;
            int k = k0 + kk;
            sW[kk][e] = (k < Ktot) ? Bt[(size_t)k * 128 + e] : 0.0f;
        }
        __syncthreads();
#pragma unroll 8
        for (int kk = 0; kk < GK; ++kk) {
            float4 a4 = *(const float4*)&sAT[kk][m0];
            float4 w4 = *(const float4*)&sW[kk][e0];
            float av[4] = {a4.x, a4.y, a4.z, a4.w};
            float wv[4] = {w4.x, w4.y, w4.z, w4.w};
#pragma unroll
            for (int i2 = 0; i2 < 4; ++i2)
#pragma unroll
                for (int j = 0; j < 4; ++j)
                    acc[i2][j] += av[i2] * wv[j];
        }
        __syncthreads();
    }
    // epilogue: add bias, store float4 per row
    float4 b4 = *(const float4*)&bias[e0];
#pragma unroll
    for (int i2 = 0; i2 < 4; ++i2) {
        int node = blockM + m0 + i2;
        float4 o;
        o.x = acc[i2][0] + b4.x;
        o.y = acc[i2][1] + b4.y;
        o.z = acc[i2][2] + b4.z;
        o.w = acc[i2][3] + b4.w;
        *(float4*)&Cout[(size_t)node * 128 + e0] = o;
    }
}

// ---------------------------------------------------------------------------
// K3: rowwise relu + L2 normalize over width 128. One 128-thread block / row.
// ---------------------------------------------------------------------------
__global__ __launch_bounds__(128) void k_relunorm(const float* __restrict__ P,
                                                  float* __restrict__ H) {
    const int r = blockIdx.x;
    const int t = threadIdx.x;
    float v = P[(size_t)r * 128 + t];
    v = fmaxf(v, 0.0f);
    float s = v * v;
#pragma unroll
    for (int off = 32; off > 0; off >>= 1) s += __shfl_down(s, off, 64);
    __shared__ float sw[2];
    if ((t & 63) == 0) sw[t >> 6] = s;
    __syncthreads();
    float tot = sw[0] + sw[1];
    float denom = fmaxf(sqrtf(tot), 1e-12f);
    H[(size_t)r * 128 + t] = v / denom;
}

// ---------------------------------------------------------------------------
// K4: layer-2 aggregation for the node batch. One 128-thread block per b.
// h2[b][0:128] = H1[node];  h2[b][128:256] = mean_{j in nbr(node)} H1[j]
// ---------------------------------------------------------------------------
__global__ __launch_bounds__(128) void k_agg2(const int* __restrict__ nodes,
                                              const float* __restrict__ adj,
                                              const float* __restrict__ H1,
                                              float* __restrict__ h2) {
    const int b = blockIdx.x;
    const int node = nodes[b];
    const float* row = adj + (size_t)node * N_NODES;
    __shared__ int s_cnt;
    __shared__ int s_idx[256];
    if (threadIdx.x == 0) s_cnt = 0;
    __syncthreads();
    // 16384 floats / (128 thr * 4) = 32 passes
    for (int base = 0; base < N_NODES; base += 512) {
        float4 v = ((const float4*)(row + base))[threadIdx.x];
        int col = base + threadIdx.x * 4;
        if (v.x != 0.0f) { int p = atomicAdd(&s_cnt, 1); if (p < 256) s_idx[p] = col;     }
        if (v.y != 0.0f) { int p = atomicAdd(&s_cnt, 1); if (p < 256) s_idx[p] = col + 1; }
        if (v.z != 0.0f) { int p = atomicAdd(&s_cnt, 1); if (p < 256) s_idx[p] = col + 2; }
        if (v.w != 0.0f) { int p = atomicAdd(&s_cnt, 1); if (p < 256) s_idx[p] = col + 3; }
    }
    __syncthreads();
    const int cnt = s_cnt;
    const int t = threadIdx.x;
    float acc = 0.0f;
    for (int k = 0; k < cnt; ++k) acc += H1[(size_t)s_idx[k] * 128 + t];
    h2[(size_t)b * 256 + t]       = H1[(size_t)node * 128 + t];
    h2[(size_t)b * 256 + 128 + t] = acc / (float)cnt;
}

// ---------------------------------------------------------------------------
// K5: fused classifier head + softmax. One 128-thread block per batch node.
// x1 = H2 @ Wl1^T + bl1 ; x2 = x1 @ Wl2^T + bl2 ; out = softmax(x2)
// ---------------------------------------------------------------------------
__global__ __launch_bounds__(128) void k_head(const float* __restrict__ H2,
                                              const float* __restrict__ Wl1t, // [128][128]
                                              const float* __restrict__ bl1,
                                              const float* __restrict__ Wl2,  // [10][128]
                                              const float* __restrict__ bl2,
                                              float* __restrict__ out) {
    const int b = blockIdx.x;
    const int t = threadIdx.x;
    __shared__ float sh[128];
    __shared__ float sx[128];
    __shared__ float sc[16];
    sh[t] = H2[(size_t)b * 128 + t];
    __syncthreads();
    float acc = bl1[t];
    for (int k = 0; k < 128; ++k) acc += Wl1t[k * 128 + t] * sh[k];
    sx[t] = acc;
    __syncthreads();
    if (t < C_DIM) {
        float a2 = bl2[t];
        const float* wr = Wl2 + t * 128;
        for (int k = 0; k < 128; ++k) a2 += wr[k] * sx[k];
        sc[t] = a2;
    }
    __syncthreads();
    if (t < C_DIM) {
        float mx = -1e30f;
        for (int c = 0; c < C_DIM; ++c) mx = fmaxf(mx, sc[c]);
        float se = 0.0f;
        for (int c = 0; c < C_DIM; ++c) se += expf(sc[c] - mx);
        out[(size_t)b * C_DIM + t] = expf(sc[t] - mx) / se;
    }
}

// ---------------------------------------------------------------------------
// Launch
// ---------------------------------------------------------------------------
extern "C" void kernel_launch(void* const* d_in, const int* in_sizes, int n_in,
                              void* d_out, int out_size, void* d_ws, size_t ws_size,
                              hipStream_t stream) {
    const int*   nodes = (const int*)  d_in[0];
    const float* adj   = (const float*)d_in[1];
    const float* data  = (const float*)d_in[2];
    const float* W1    = (const float*)d_in[3];
    const float* b1    = (const float*)d_in[4];
    const float* W2    = (const float*)d_in[5];
    const float* b2    = (const float*)d_in[6];
    const float* Wl1   = (const float*)d_in[7];
    const float* bl1   = (const float*)d_in[8];
    const float* Wl2   = (const float*)d_in[9];
    const float* bl2   = (const float*)d_in[10];
    float* out = (float*)d_out;

    float* ws = (float*)d_ws;
    // workspace layout (floats)
    float* W1t    = ws;                         // 1000*128   = 128000
    float* W2t    = W1t  + 128000;              // 256*128    = 32768
    float* Wl1t   = W2t  + 32768;               // 128*128    = 16384
    float* neigh1 = Wl1t + 16384;               // 16384*500  = 8192000
    float* P1     = neigh1 + 8192000;           // 16384*128  = 2097152
    float* H1     = P1   + 2097152;             // 16384*128  = 2097152
    float* h2     = neigh1;                     // reuse (neigh1 dead after GEMM1): 4096*256
    float* P2     = P1;                         // reuse (P1 dead after relunorm1): 4096*128
    float* H2     = P1 + 524288;                // within old P1 region: 4096*128

    // transposes
    k_transpose<<<(128 * 1000 + 255) / 256, 256, 0, stream>>>(W1, W1t, E_DIM, 2 * F_DIM);
    k_transpose<<<(128 * 256 + 255) / 256, 256, 0, stream>>>(W2, W2t, E_DIM, 2 * E_DIM);
    k_transpose<<<(128 * 128 + 255) / 256, 256, 0, stream>>>(Wl1, Wl1t, LIN_DIM, E_DIM);

    // layer 1
    k_agg1<<<N_NODES, 256, 0, stream>>>(adj, data, neigh1);
    k_gemm<<<N_NODES / GM, 256, 0, stream>>>(data, F_DIM, neigh1, 2 * F_DIM, W1t, b1, P1, N_NODES);
    k_relunorm<<<N_NODES, 128, 0, stream>>>(P1, H1);

    // layer 2 (batch only)
    k_agg2<<<B_DIM, 128, 0, stream>>>(nodes, adj, H1, h2);
    k_gemm<<<B_DIM / GM, 256, 0, stream>>>(h2, 2 * E_DIM, h2, 2 * E_DIM, W2t, b2, P2, B_DIM);
    k_relunorm<<<B_DIM, 128, 0, stream>>>(P2, H2);

    // head
    k_head<<<B_DIM, 128, 0, stream>>>(H2, Wl1t, bl1, Wl2, bl2, out);
}

// Round 2
// 1530.279 us; speedup vs baseline: 1.2247x; 1.2247x over previous
//
#include <hip/hip_runtime.h>
#include <math.h>
#include <stddef.h>

#define N_NODES 16384
#define F_DIM   500
#define E_DIM   128
#define C_DIM   10
#define B_DIM   4096
#define MAXDEG  128

// ---------------------------------------------------------------------------
// Weight prep: build K-major stacked layouts for coalesced GEMM B-tiles.
// W1s[k][e] (k<500, e<256): e<128 -> W1[e][k] ; e>=128 -> W1[e-128][500+k]
// ---------------------------------------------------------------------------
__global__ void k_prep_w1(const float* __restrict__ W1, float* __restrict__ W1s) {
    int idx = blockIdx.x * 256 + threadIdx.x;      // 500*256
    int e = idx & 255, k = idx >> 8;
    W1s[idx] = W1[(size_t)(e & 127) * 1000 + (e >> 7) * 500 + k];
}
// W2s[k][e] (k<128, e<256): e<128 -> W2[e][k] ; e>=128 -> W2[e-128][128+k]
__global__ void k_prep_w2(const float* __restrict__ W2, float* __restrict__ W2s) {
    int idx = blockIdx.x * 256 + threadIdx.x;      // 128*256
    int e = idx & 255, k = idx >> 8;
    W2s[idx] = W2[(size_t)(e & 127) * 256 + (e >> 7) * 128 + k];
}
// Wl1t[k][e] = Wl1[e][k]  (128x128)
__global__ void k_prep_wl1(const float* __restrict__ Wl1, float* __restrict__ Wl1t) {
    int idx = blockIdx.x * 256 + threadIdx.x;      // 128*128
    int e = idx & 127, k = idx >> 7;
    Wl1t[idx] = Wl1[(size_t)e * 128 + k];
}

// ---------------------------------------------------------------------------
// fp32 GEMM: C[M][256] = A[M][K] @ Bs[K][256].  Tile 32x256, 256 thr,
// micro 4 rows x (4+4) cols. Grid = M/32 (M multiple of 32).
// ---------------------------------------------------------------------------
__global__ __launch_bounds__(256) void k_gemm_s(const float* __restrict__ A, int K,
                                                const float* __restrict__ Bs,
                                                float* __restrict__ Cout) {
    __shared__ float sAT[32][36];     // [kk][m], stride 36 floats (16B-aligned rows)
    __shared__ float sW[32][256];
    const int tid = threadIdx.x;
    const int c0 = (tid & 31) * 4;    // cols c0..c0+3 and c0+128..c0+131
    const int r0 = (tid >> 5) * 4;    // rows r0..r0+3
    const int blockM = blockIdx.x * 32;
    const int kk_s = tid & 31;
    const int mm_s = tid >> 5;
    float acc[4][8] = {};

    for (int k0 = 0; k0 < K; k0 += 32) {
        // stage A tile (transposed)
#pragma unroll
        for (int r = 0; r < 4; ++r) {
            int m = mm_s + r * 8;
            int k = k0 + kk_s;
            sAT[kk_s][m] = (k < K) ? A[(size_t)(blockM + m) * K + k] : 0.0f;
        }
        // stage W tile, float4 (8192 floats = 2048 float4, 8 per thread)
#pragma unroll
        for (int q = 0; q < 8; ++q) {
            int idx4 = tid + 256 * q;
            int row = idx4 >> 6;
            int e4 = idx4 & 63;
            float4 w;
            if (k0 + row < K) w = ((const float4*)(Bs + (size_t)(k0 + row) * 256))[e4];
            else              w = make_float4(0.f, 0.f, 0.f, 0.f);
            *(float4*)&sW[row][e4 * 4] = w;
        }
        __syncthreads();
#pragma unroll 8
        for (int kk = 0; kk < 32; ++kk) {
            float4 a4 = *(const float4*)&sAT[kk][r0];
            float4 w0 = *(const float4*)&sW[kk][c0];
            float4 w1 = *(const float4*)&sW[kk][c0 + 128];
            float av[4] = {a4.x, a4.y, a4.z, a4.w};
            float wv[8] = {w0.x, w0.y, w0.z, w0.w, w1.x, w1.y, w1.z, w1.w};
#pragma unroll
            for (int i = 0; i < 4; ++i)
#pragma unroll
                for (int j = 0; j < 8; ++j)
                    acc[i][j] += av[i] * wv[j];
        }
        __syncthreads();
    }
#pragma unroll
    for (int i = 0; i < 4; ++i) {
        size_t base = (size_t)(blockM + r0 + i) * 256;
        *(float4*)&Cout[base + c0]       = make_float4(acc[i][0], acc[i][1], acc[i][2], acc[i][3]);
        *(float4*)&Cout[base + c0 + 128] = make_float4(acc[i][4], acc[i][5], acc[i][6], acc[i][7]);
    }
}

// ---------------------------------------------------------------------------
// Layer-1 fused: per node i — scan adj row (prefetch 16 float4/thread),
// collect nonzero cols (== neighbor idx, adj entries are exactly 1.0),
// cache CSR for layer 2, then H1[i] = l2norm(relu(Xa[i] + mean_j Xb[j] + b1)).
// X layout: X[i][0:128]=Xa=data@W1a^T, X[i][128:256]=Xb=data@W1b^T.
// ---------------------------------------------------------------------------
__global__ __launch_bounds__(256) void k_agg1(const float* __restrict__ adj,
                                              const float* __restrict__ X,
                                              const float* __restrict__ b1,
                                              float* __restrict__ H1,
                                              int* __restrict__ nbr,
                                              int* __restrict__ deg) {
    const int i = blockIdx.x;
    const int t = threadIdx.x;
    const float4* row4 = (const float4*)(adj + (size_t)i * N_NODES);
    __shared__ int s_cnt;
    __shared__ int s_idx[MAXDEG];
    __shared__ float s_part[2][128];
    __shared__ float s_w[2];
    if (t == 0) s_cnt = 0;
    __syncthreads();
    // prefetch entire row slice: 16 outstanding float4 loads per thread
    float4 v[16];
#pragma unroll
    for (int p = 0; p < 16; ++p) v[p] = row4[p * 256 + t];
#pragma unroll
    for (int p = 0; p < 16; ++p) {
        int col = p * 1024 + t * 4;
        if (v[p].x != 0.f) { int q = atomicAdd(&s_cnt, 1); if (q < MAXDEG) s_idx[q] = col;     }
        if (v[p].y != 0.f) { int q = atomicAdd(&s_cnt, 1); if (q < MAXDEG) s_idx[q] = col + 1; }
        if (v[p].z != 0.f) { int q = atomicAdd(&s_cnt, 1); if (q < MAXDEG) s_idx[q] = col + 2; }
        if (v[p].w != 0.f) { int q = atomicAdd(&s_cnt, 1); if (q < MAXDEG) s_idx[q] = col + 3; }
    }
    __syncthreads();
    int cnt = s_cnt; if (cnt > MAXDEG) cnt = MAXDEG;   // deg>=1 (self-loop)
    if (t < cnt) nbr[(size_t)i * MAXDEG + t] = s_idx[t];
    if (t == 0) deg[i] = cnt;
    const float inv = 1.0f / (float)cnt;
    // gather Xb rows: 2 groups of 128 threads split the neighbor list
    const int col = t & 127;
    const int g = t >> 7;
    float acc = 0.f;
    for (int k = g; k < cnt; k += 2)
        acc += X[(size_t)s_idx[k] * 256 + 128 + col];
    s_part[g][col] = acc;
    __syncthreads();
    float vv = 0.f;
    if (t < 128) {
        float tot = s_part[0][t] + s_part[1][t];
        vv = X[(size_t)i * 256 + t] + tot * inv + b1[t];
        vv = fmaxf(vv, 0.f);
        float s = vv * vv;
#pragma unroll
        for (int off = 32; off > 0; off >>= 1) s += __shfl_down(s, off, 64);
        if ((t & 63) == 0) s_w[t >> 6] = s;
    }
    __syncthreads();
    if (t < 128) {
        float denom = fmaxf(sqrtf(s_w[0] + s_w[1]), 1e-12f);
        H1[(size_t)i * 128 + t] = vv / denom;
    }
}

// ---------------------------------------------------------------------------
// Layer-2 + head fused, per batch node b (128 threads). Uses cached CSR —
// zero adj bytes. Y[i][0:128]=Ya=H1@W2a^T, Y[i][128:256]=Yb=H1@W2b^T.
// H2 = l2norm(relu(Ya[n] + mean_j Yb[j] + b2)); then Wl1/Wl2 + softmax.
// ---------------------------------------------------------------------------
__global__ __launch_bounds__(128) void k_l2head(const int* __restrict__ nodes,
                                                const int* __restrict__ nbr,
                                                const int* __restrict__ deg,
                                                const float* __restrict__ Y,
                                                const float* __restrict__ b2,
                                                const float* __restrict__ Wl1t,
                                                const float* __restrict__ bl1,
                                                const float* __restrict__ Wl2,
                                                const float* __restrict__ bl2,
                                                float* __restrict__ out) {
    const int b = blockIdx.x;
    const int t = threadIdx.x;
    const int n = nodes[b];
    const int cnt = deg[n];
    __shared__ int s_idx[MAXDEG];
    __shared__ float s_h[128];
    __shared__ float s_x[128];
    __shared__ float s_c[C_DIM];
    __shared__ float s_w[2];
    if (t < cnt) s_idx[t] = nbr[(size_t)n * MAXDEG + t];
    __syncthreads();
    float a0 = 0.f, a1 = 0.f;
    int k = 0;
    for (; k + 1 < cnt; k += 2) {
        a0 += Y[(size_t)s_idx[k]     * 256 + 128 + t];
        a1 += Y[(size_t)s_idx[k + 1] * 256 + 128 + t];
    }
    if (k < cnt) a0 += Y[(size_t)s_idx[k] * 256 + 128 + t];
    float vv = Y[(size_t)n * 256 + t] + (a0 + a1) / (float)cnt + b2[t];
    vv = fmaxf(vv, 0.f);
    float s = vv * vv;
#pragma unroll
    for (int off = 32; off > 0; off >>= 1) s += __shfl_down(s, off, 64);
    if ((t & 63) == 0) s_w[t >> 6] = s;
    __syncthreads();
    float denom = fmaxf(sqrtf(s_w[0] + s_w[1]), 1e-12f);
    s_h[t] = vv / denom;
    __syncthreads();
    float x1 = bl1[t];
#pragma unroll 8
    for (int kk = 0; kk < 128; ++kk)
        x1 += Wl1t[kk * 128 + t] * s_h[kk];
    s_x[t] = x1;
    __syncthreads();
    if (t < C_DIM) {
        float l = bl2[t];
        const float* wr = Wl2 + (size_t)t * 128;
        for (int kk = 0; kk < 128; ++kk) l += wr[kk] * s_x[kk];
        s_c[t] = l;
    }
    __syncthreads();
    if (t < C_DIM) {
        float mx = -1e30f;
        for (int c = 0; c < C_DIM; ++c) mx = fmaxf(mx, s_c[c]);
        float se = 0.f;
        for (int c = 0; c < C_DIM; ++c) se += expf(s_c[c] - mx);
        out[(size_t)b * C_DIM + t] = expf(s_c[t] - mx) / se;
    }
}

// ---------------------------------------------------------------------------
// Launch
// ---------------------------------------------------------------------------
extern "C" void kernel_launch(void* const* d_in, const int* in_sizes, int n_in,
                              void* d_out, int out_size, void* d_ws, size_t ws_size,
                              hipStream_t stream) {
    const int*   nodes = (const int*)  d_in[0];
    const float* adj   = (const float*)d_in[1];
    const float* data  = (const float*)d_in[2];
    const float* W1    = (const float*)d_in[3];
    const float* b1    = (const float*)d_in[4];
    const float* W2    = (const float*)d_in[5];
    const float* b2    = (const float*)d_in[6];
    const float* Wl1   = (const float*)d_in[7];
    const float* bl1   = (const float*)d_in[8];
    const float* Wl2   = (const float*)d_in[9];
    const float* bl2   = (const float*)d_in[10];
    float* out = (float*)d_out;

    float* ws = (float*)d_ws;
    float* W1s  = ws;                      // 500*256   = 128000
    float* W2s  = W1s  + 128000;           // 128*256   = 32768
    float* Wl1t = W2s  + 32768;            // 128*128   = 16384
    float* X    = Wl1t + 16384;            // 16384*256 = 4194304
    float* H1   = X    + 4194304;          // 16384*128 = 2097152
    float* Y    = H1   + 2097152;          // 16384*256 = 4194304
    int*   nbr  = (int*)(Y + 4194304);     // 16384*128 ints
    int*   deg  = nbr  + 16384 * MAXDEG;   // 16384 ints

    // weight prep
    k_prep_w1 <<<500, 256, 0, stream>>>(W1, W1s);
    k_prep_w2 <<<128, 256, 0, stream>>>(W2, W2s);
    k_prep_wl1<<<64,  256, 0, stream>>>(Wl1, Wl1t);

    // layer 1: GEMM first (linearity of mean-agg), then fused scan+agg+norm
    k_gemm_s<<<N_NODES / 32, 256, 0, stream>>>(data, F_DIM, W1s, X);
    k_agg1  <<<N_NODES, 256, 0, stream>>>(adj, X, b1, H1, nbr, deg);

    // layer 2: GEMM on all nodes (cheap), then fused agg+norm+head per batch node
    k_gemm_s<<<N_NODES / 32, 256, 0, stream>>>(H1, E_DIM, W2s, Y);
    k_l2head<<<B_DIM, 128, 0, stream>>>(nodes, nbr, deg, Y, b2, Wl1t, bl1, Wl2, bl2, out);
}

// Round 3
// 1503.614 us; speedup vs baseline: 1.2464x; 1.0177x over previous
//
#include <hip/hip_runtime.h>
#include <math.h>
#include <stddef.h>

#define N_NODES 16384
#define F_DIM   500
#define E_DIM   128
#define C_DIM   10
#define B_DIM   4096
#define MAXDEG  128

// ---------------------------------------------------------------------------
// Tiled transpose: dst[k][eOff+e] = src[e*srcStride + cOff + k]
// src block is R(=128) rows x Kc cols; dst has row stride dstStride floats.
// Grid: (ceil(Kc/32), R/32). Block: (32,8), each thread does 4 rows.
// ---------------------------------------------------------------------------
__global__ void k_tp(const float* __restrict__ src, float* __restrict__ dst,
                     int srcStride, int cOff, int Kc, int eOff, int dstStride) {
    __shared__ float tile[32][33];
    const int k0 = blockIdx.x * 32;
    const int e0 = blockIdx.y * 32;
    const int tx = threadIdx.x, ty0 = threadIdx.y;
#pragma unroll
    for (int q = 0; q < 4; ++q) {
        int ty = ty0 + q * 8;
        int k = k0 + tx;
        tile[ty][tx] = (k < Kc) ? src[(size_t)(e0 + ty) * srcStride + cOff + k] : 0.0f;
    }
    __syncthreads();
#pragma unroll
    for (int q = 0; q < 4; ++q) {
        int ty = ty0 + q * 8;
        int k = k0 + ty;
        if (k < Kc) dst[(size_t)k * dstStride + eOff + e0 + tx] = tile[tx][ty];
    }
}

// ---------------------------------------------------------------------------
// fp32 GEMM: C[M][256] = A[M][K] @ Bs[K][256].
// Tile 64 rows x 256 cols, K-chunk 32. 256 threads; micro-tile 8 rows x
// (4+4) cols (c0 and c0+128 -> lane word-stride 4 in LDS = mild 4-way).
// Register-prefetch pipeline hides global staging latency.
// ---------------------------------------------------------------------------
__global__ __launch_bounds__(256) void k_gemm_s(const float* __restrict__ A, int K,
                                                const float* __restrict__ Bs,
                                                float* __restrict__ Cout) {
    __shared__ float sAT[32][68];     // [kk][m], stride 272B (16B aligned)
    __shared__ float sW[32][256];
    const int tid = threadIdx.x;
    const int c0 = (tid & 31) * 4;    // cols c0..c0+3 and c0+128..+131
    const int r0 = (tid >> 5) * 8;    // rows r0..r0+7
    const int blockM = blockIdx.x * 64;
    const int kk_s = tid & 31;        // staging: k offset
    const int mg_s = (tid >> 5) * 8;  // staging: row group base
    float acc[8][8] = {};
    float  pa[8];
    float4 pw[8];

    const int nch = (K + 31) >> 5;

    // ---- staging helpers ----
    auto loadG = [&](int k0) {
        int k = k0 + kk_s;
#pragma unroll
        for (int r = 0; r < 8; ++r)
            pa[r] = (k < K) ? A[(size_t)(blockM + mg_s + r) * K + k] : 0.0f;
#pragma unroll
        for (int q = 0; q < 8; ++q) {
            int idx4 = tid + 256 * q;
            int row = idx4 >> 6, e4 = idx4 & 63;
            pw[q] = (k0 + row < K) ? ((const float4*)(Bs + (size_t)(k0 + row) * 256))[e4]
                                   : make_float4(0.f, 0.f, 0.f, 0.f);
        }
    };
    auto storeL = [&]() {
#pragma unroll
        for (int r = 0; r < 8; ++r) sAT[kk_s][mg_s + r] = pa[r];
#pragma unroll
        for (int q = 0; q < 8; ++q) {
            int idx4 = tid + 256 * q;
            int row = idx4 >> 6, e4 = idx4 & 63;
            *(float4*)&sW[row][e4 * 4] = pw[q];
        }
    };

    loadG(0);
    storeL();
    __syncthreads();

    for (int c = 1; c <= nch; ++c) {
        const bool more = (c < nch);
        if (more) loadG(c * 32);      // in flight during compute
#pragma unroll 8
        for (int kk = 0; kk < 32; ++kk) {
            float4 a0 = *(const float4*)&sAT[kk][r0];
            float4 a1 = *(const float4*)&sAT[kk][r0 + 4];
            float4 w0 = *(const float4*)&sW[kk][c0];
            float4 w1 = *(const float4*)&sW[kk][c0 + 128];
            float av[8] = {a0.x, a0.y, a0.z, a0.w, a1.x, a1.y, a1.z, a1.w};
            float wv[8] = {w0.x, w0.y, w0.z, w0.w, w1.x, w1.y, w1.z, w1.w};
#pragma unroll
            for (int i = 0; i < 8; ++i)
#pragma unroll
                for (int j = 0; j < 8; ++j)
                    acc[i][j] += av[i] * wv[j];
        }
        if (more) {
            __syncthreads();          // all waves done reading LDS
            storeL();
            __syncthreads();
        }
    }
#pragma unroll
    for (int i = 0; i < 8; ++i) {
        size_t base = (size_t)(blockM + r0 + i) * 256;
        *(float4*)&Cout[base + c0]       = make_float4(acc[i][0], acc[i][1], acc[i][2], acc[i][3]);
        *(float4*)&Cout[base + c0 + 128] = make_float4(acc[i][4], acc[i][5], acc[i][6], acc[i][7]);
    }
}

// ---------------------------------------------------------------------------
// Layer-1 fused: per node i — scan adj row (prefetch 16 float4/thread),
// collect nonzero cols, cache CSR for layer 2, then
// H1[i] = l2norm(relu(Xa[i] + mean_j Xb[j] + b1)).
// X layout: X[i][0:128]=Xa=data@W1a^T, X[i][128:256]=Xb=data@W1b^T.
// ---------------------------------------------------------------------------
__global__ __launch_bounds__(256) void k_agg1(const float* __restrict__ adj,
                                              const float* __restrict__ X,
                                              const float* __restrict__ b1,
                                              float* __restrict__ H1,
                                              int* __restrict__ nbr,
                                              int* __restrict__ deg) {
    const int i = blockIdx.x;
    const int t = threadIdx.x;
    const float4* row4 = (const float4*)(adj + (size_t)i * N_NODES);
    __shared__ int s_cnt;
    __shared__ int s_idx[MAXDEG];
    __shared__ float s_part[2][128];
    __shared__ float s_w[2];
    if (t == 0) s_cnt = 0;
    __syncthreads();
    float4 v[16];
#pragma unroll
    for (int p = 0; p < 16; ++p) v[p] = row4[p * 256 + t];
#pragma unroll
    for (int p = 0; p < 16; ++p) {
        int col = p * 1024 + t * 4;
        if (v[p].x != 0.f) { int q = atomicAdd(&s_cnt, 1); if (q < MAXDEG) s_idx[q] = col;     }
        if (v[p].y != 0.f) { int q = atomicAdd(&s_cnt, 1); if (q < MAXDEG) s_idx[q] = col + 1; }
        if (v[p].z != 0.f) { int q = atomicAdd(&s_cnt, 1); if (q < MAXDEG) s_idx[q] = col + 2; }
        if (v[p].w != 0.f) { int q = atomicAdd(&s_cnt, 1); if (q < MAXDEG) s_idx[q] = col + 3; }
    }
    __syncthreads();
    int cnt = s_cnt; if (cnt > MAXDEG) cnt = MAXDEG;   // deg>=1 (self-loop)
    if (t < cnt) nbr[(size_t)i * MAXDEG + t] = s_idx[t];
    if (t == 0) deg[i] = cnt;
    const float inv = 1.0f / (float)cnt;
    const int col = t & 127;
    const int g = t >> 7;
    float acc = 0.f;
    for (int k = g; k < cnt; k += 2)
        acc += X[(size_t)s_idx[k] * 256 + 128 + col];
    s_part[g][col] = acc;
    __syncthreads();
    float vv = 0.f;
    if (t < 128) {
        float tot = s_part[0][t] + s_part[1][t];
        vv = X[(size_t)i * 256 + t] + tot * inv + b1[t];
        vv = fmaxf(vv, 0.f);
        float s = vv * vv;
#pragma unroll
        for (int off = 32; off > 0; off >>= 1) s += __shfl_down(s, off, 64);
        if ((t & 63) == 0) s_w[t >> 6] = s;
    }
    __syncthreads();
    if (t < 128) {
        float denom = fmaxf(sqrtf(s_w[0] + s_w[1]), 1e-12f);
        H1[(size_t)i * 128 + t] = vv / denom;
    }
}

// ---------------------------------------------------------------------------
// Layer-2 + head fused, per batch node b (128 threads). Cached CSR — zero
// adj bytes. Y[i][0:128]=Ya=H1@W2a^T, Y[i][128:256]=Yb=H1@W2b^T.
// ---------------------------------------------------------------------------
__global__ __launch_bounds__(128) void k_l2head(const int* __restrict__ nodes,
                                                const int* __restrict__ nbr,
                                                const int* __restrict__ deg,
                                                const float* __restrict__ Y,
                                                const float* __restrict__ b2,
                                                const float* __restrict__ Wl1t,
                                                const float* __restrict__ bl1,
                                                const float* __restrict__ Wl2,
                                                const float* __restrict__ bl2,
                                                float* __restrict__ out) {
    const int b = blockIdx.x;
    const int t = threadIdx.x;
    const int n = nodes[b];
    const int cnt = deg[n];
    __shared__ int s_idx[MAXDEG];
    __shared__ float s_h[128];
    __shared__ float s_x[128];
    __shared__ float s_c[C_DIM];
    __shared__ float s_w[2];
    if (t < cnt) s_idx[t] = nbr[(size_t)n * MAXDEG + t];
    __syncthreads();
    float a0 = 0.f, a1 = 0.f;
    int k = 0;
    for (; k + 1 < cnt; k += 2) {
        a0 += Y[(size_t)s_idx[k]     * 256 + 128 + t];
        a1 += Y[(size_t)s_idx[k + 1] * 256 + 128 + t];
    }
    if (k < cnt) a0 += Y[(size_t)s_idx[k] * 256 + 128 + t];
    float vv = Y[(size_t)n * 256 + t] + (a0 + a1) / (float)cnt + b2[t];
    vv = fmaxf(vv, 0.f);
    float s = vv * vv;
#pragma unroll
    for (int off = 32; off > 0; off >>= 1) s += __shfl_down(s, off, 64);
    if ((t & 63) == 0) s_w[t >> 6] = s;
    __syncthreads();
    float denom = fmaxf(sqrtf(s_w[0] + s_w[1]), 1e-12f);
    s_h[t] = vv / denom;
    __syncthreads();
    float x1 = bl1[t];
#pragma unroll 8
    for (int kk = 0; kk < 128; ++kk)
        x1 += Wl1t[kk * 128 + t] * s_h[kk];
    s_x[t] = x1;
    __syncthreads();
    if (t < C_DIM) {
        float l = bl2[t];
        const float* wr = Wl2 + (size_t)t * 128;
        for (int kk = 0; kk < 128; ++kk) l += wr[kk] * s_x[kk];
        s_c[t] = l;
    }
    __syncthreads();
    if (t < C_DIM) {
        float mx = -1e30f;
        for (int c = 0; c < C_DIM; ++c) mx = fmaxf(mx, s_c[c]);
        float se = 0.f;
        for (int c = 0; c < C_DIM; ++c) se += expf(s_c[c] - mx);
        out[(size_t)b * C_DIM + t] = expf(s_c[t] - mx) / se;
    }
}

// ---------------------------------------------------------------------------
// Launch
// ---------------------------------------------------------------------------
extern "C" void kernel_launch(void* const* d_in, const int* in_sizes, int n_in,
                              void* d_out, int out_size, void* d_ws, size_t ws_size,
                              hipStream_t stream) {
    const int*   nodes = (const int*)  d_in[0];
    const float* adj   = (const float*)d_in[1];
    const float* data  = (const float*)d_in[2];
    const float* W1    = (const float*)d_in[3];
    const float* b1    = (const float*)d_in[4];
    const float* W2    = (const float*)d_in[5];
    const float* b2    = (const float*)d_in[6];
    const float* Wl1   = (const float*)d_in[7];
    const float* bl1   = (const float*)d_in[8];
    const float* Wl2   = (const float*)d_in[9];
    const float* bl2   = (const float*)d_in[10];
    float* out = (float*)d_out;

    float* ws = (float*)d_ws;
    float* W1s  = ws;                      // 500*256   = 128000
    float* W2s  = W1s  + 128000;           // 128*256   = 32768
    float* Wl1t = W2s  + 32768;            // 128*128   = 16384
    float* X    = Wl1t + 16384;            // 16384*256 = 4194304
    float* H1   = X    + 4194304;          // 16384*128 = 2097152
    float* Y    = H1   + 2097152;          // 16384*256 = 4194304
    int*   nbr  = (int*)(Y + 4194304);     // 16384*128 ints
    int*   deg  = nbr  + 16384 * MAXDEG;   // 16384 ints

    // weight prep (tiled transposes, coalesced both sides)
    dim3 tpb(32, 8);
    k_tp<<<dim3(16, 4), tpb, 0, stream>>>(W1, W1s, 1000, 0,   500, 0,   256); // W1a
    k_tp<<<dim3(16, 4), tpb, 0, stream>>>(W1, W1s, 1000, 500, 500, 128, 256); // W1b
    k_tp<<<dim3(4, 4),  tpb, 0, stream>>>(W2, W2s, 256,  0,   128, 0,   256); // W2a
    k_tp<<<dim3(4, 4),  tpb, 0, stream>>>(W2, W2s, 256,  128, 128, 128, 256); // W2b
    k_tp<<<dim3(4, 4),  tpb, 0, stream>>>(Wl1, Wl1t, 128, 0,  128, 0,   128); // Wl1^T

    // layer 1: GEMM first (linearity of mean-agg), then fused scan+agg+norm
    k_gemm_s<<<N_NODES / 64, 256, 0, stream>>>(data, F_DIM, W1s, X);
    k_agg1  <<<N_NODES, 256, 0, stream>>>(adj, X, b1, H1, nbr, deg);

    // layer 2: GEMM on all nodes, then fused agg+norm+head per batch node
    k_gemm_s<<<N_NODES / 64, 256, 0, stream>>>(H1, E_DIM, W2s, Y);
    k_l2head<<<B_DIM, 128, 0, stream>>>(nodes, nbr, deg, Y, b2, Wl1t, bl1, Wl2, bl2, out);
}

// Round 4
// 1443.477 us; speedup vs baseline: 1.2983x; 1.0417x over previous
//
#include <hip/hip_runtime.h>
#include <math.h>
#include <stddef.h>

#define N_NODES 16384
#define F_DIM   500
#define KP1     512
#define E_DIM   128
#define C_DIM   10
#define B_DIM   4096
#define MAXDEG  128

typedef __attribute__((ext_vector_type(8))) short short8;   // 8 bf16 = 4 VGPRs
typedef __attribute__((ext_vector_type(4))) float f32x4;    // MFMA C/D

__device__ inline unsigned short f2bf(float f) {
    union { float f; unsigned int u; } v; v.f = f;
    unsigned int u = v.u;
    u += 0x7FFFu + ((u >> 16) & 1u);        // RNE
    return (unsigned short)(u >> 16);
}

// ---------------------------------------------------------------------------
// Cast data [16384][500] fp32 -> Ab [16384][512] bf16 (zero-padded K).
// ---------------------------------------------------------------------------
__global__ __launch_bounds__(256) void k_cast_data(const float* __restrict__ src,
                                                   unsigned short* __restrict__ dst) {
    int idx = blockIdx.x * 256 + threadIdx.x;     // over 16384*256
    int i = idx >> 8, k2 = (idx & 255) * 2;
    unsigned short a = 0, b = 0;
    if (k2 < F_DIM) {
        float2 d = *(const float2*)(src + (size_t)i * F_DIM + k2);
        a = f2bf(d.x); b = f2bf(d.y);
    }
    ushort2 o; o.x = a; o.y = b;
    *(ushort2*)(dst + (size_t)i * KP1 + k2) = o;
}

// Wt1 [256][512] bf16: row n<128 -> W1[n][0:500]; n>=128 -> W1[n-128][500:1000]
__global__ __launch_bounds__(256) void k_prep_w1b(const float* __restrict__ W1,
                                                  unsigned short* __restrict__ Wt) {
    int idx = blockIdx.x * 256 + threadIdx.x;     // 256*512
    int n = idx >> 9, k = idx & 511;
    float v = (k < F_DIM) ? W1[(size_t)(n & 127) * 1000 + (n >> 7) * F_DIM + k] : 0.0f;
    Wt[idx] = f2bf(v);
}

// Wt2 [256][128] bf16: row n<128 -> W2[n][0:128]; n>=128 -> W2[n-128][128:256]
__global__ __launch_bounds__(256) void k_prep_w2b(const float* __restrict__ W2,
                                                  unsigned short* __restrict__ Wt) {
    int idx = blockIdx.x * 256 + threadIdx.x;     // 256*128
    int n = idx >> 7, k = idx & 127;
    Wt[idx] = f2bf(W2[(size_t)(n & 127) * 256 + (n >> 7) * 128 + k]);
}

// Wl1t[k][e] = Wl1[e][k]  (128x128 fp32, tiled transpose)
__global__ void k_tp(const float* __restrict__ src, float* __restrict__ dst) {
    __shared__ float tile[32][33];
    const int k0 = blockIdx.x * 32;
    const int e0 = blockIdx.y * 32;
    const int tx = threadIdx.x, ty0 = threadIdx.y;
#pragma unroll
    for (int q = 0; q < 4; ++q) {
        int ty = ty0 + q * 8;
        tile[ty][tx] = src[(size_t)(e0 + ty) * 128 + k0 + tx];
    }
    __syncthreads();
#pragma unroll
    for (int q = 0; q < 4; ++q) {
        int ty = ty0 + q * 8;
        dst[(size_t)(k0 + ty) * 128 + e0 + tx] = tile[tx][ty];
    }
}

// ---------------------------------------------------------------------------
// MFMA bf16 GEMM: Cout[M][256] = A[M][K]bf16 @ B^T[256][K]bf16, fp32 out.
// K = row stride of BOTH A and B^T, multiple of 32 (512 or 128).
// Tile 32x256, 256 thr (4 waves); wave w covers cols w*64..w*64+63.
// Per wave: 2 m-tiles x 4 n-tiles of 16x16 via v_mfma_f32_16x16x32_bf16.
// LDS rows padded to 40 bf16 (20-word stride -> <=2-way bank aliasing).
// ---------------------------------------------------------------------------
__global__ __launch_bounds__(256) void k_gemm_mfma(const unsigned short* __restrict__ A,
                                                   const unsigned short* __restrict__ B,
                                                   int K,
                                                   float* __restrict__ Cout) {
    __shared__ unsigned short sA[32 * 40];
    __shared__ unsigned short sB[256 * 40];
    const int tid  = threadIdx.x;
    const int w    = tid >> 6;
    const int lane = tid & 63;
    const int l16  = lane & 15;
    const int quad = lane >> 4;
    const int blockM = blockIdx.x * 32;
    f32x4 acc[2][4] = {};
    const int nchunks = K >> 5;

    for (int c = 0; c < nchunks; ++c) {
        const int k0 = c << 5;
        if (tid < 128) {                       // A tile: 32 rows x 32 bf16
            int row = tid >> 2, cc = tid & 3;
            short8 v = *(const short8*)(A + (size_t)(blockM + row) * K + k0 + cc * 8);
            *(short8*)(sA + row * 40 + cc * 8) = v;
        }
#pragma unroll
        for (int q = 0; q < 4; ++q) {          // B tile: 256 rows x 32 bf16
            int idx = tid + 256 * q;
            int row = idx >> 2, cc = idx & 3;
            short8 v = *(const short8*)(B + (size_t)row * K + k0 + cc * 8);
            *(short8*)(sB + row * 40 + cc * 8) = v;
        }
        __syncthreads();
        short8 af[2], bf[4];
#pragma unroll
        for (int mt = 0; mt < 2; ++mt)
            af[mt] = *(const short8*)(sA + (mt * 16 + l16) * 40 + quad * 8);
#pragma unroll
        for (int nt = 0; nt < 4; ++nt)
            bf[nt] = *(const short8*)(sB + (w * 64 + nt * 16 + l16) * 40 + quad * 8);
#pragma unroll
        for (int mt = 0; mt < 2; ++mt)
#pragma unroll
            for (int nt = 0; nt < 4; ++nt)
                acc[mt][nt] = __builtin_amdgcn_mfma_f32_16x16x32_bf16(af[mt], bf[nt], acc[mt][nt], 0, 0, 0);
        __syncthreads();
    }
    // C/D layout: col = lane&15, row = quad*4 + reg   [verified m89/m91]
#pragma unroll
    for (int mt = 0; mt < 2; ++mt)
#pragma unroll
        for (int nt = 0; nt < 4; ++nt) {
            int col = w * 64 + nt * 16 + l16;
#pragma unroll
            for (int r = 0; r < 4; ++r) {
                int row = blockM + mt * 16 + quad * 4 + r;
                Cout[(size_t)row * 256 + col] = acc[mt][nt][r];
            }
        }
}

// ---------------------------------------------------------------------------
// Layer-1 fused: scan adj row, cache CSR, aggregate Xb, relu+l2norm.
// Emits H1 as bf16 (GEMM2's A operand). X: [i][0:128]=Xa, [i][128:256]=Xb.
// ---------------------------------------------------------------------------
__global__ __launch_bounds__(256) void k_agg1(const float* __restrict__ adj,
                                              const float* __restrict__ X,
                                              const float* __restrict__ b1,
                                              unsigned short* __restrict__ H1b,
                                              int* __restrict__ nbr,
                                              int* __restrict__ deg) {
    const int i = blockIdx.x;
    const int t = threadIdx.x;
    const float4* row4 = (const float4*)(adj + (size_t)i * N_NODES);
    __shared__ int s_cnt;
    __shared__ int s_idx[MAXDEG];
    __shared__ float s_part[2][128];
    __shared__ float s_w[2];
    if (t == 0) s_cnt = 0;
    __syncthreads();
    float4 v[16];
#pragma unroll
    for (int p = 0; p < 16; ++p) v[p] = row4[p * 256 + t];
#pragma unroll
    for (int p = 0; p < 16; ++p) {
        int col = p * 1024 + t * 4;
        if (v[p].x != 0.f) { int q = atomicAdd(&s_cnt, 1); if (q < MAXDEG) s_idx[q] = col;     }
        if (v[p].y != 0.f) { int q = atomicAdd(&s_cnt, 1); if (q < MAXDEG) s_idx[q] = col + 1; }
        if (v[p].z != 0.f) { int q = atomicAdd(&s_cnt, 1); if (q < MAXDEG) s_idx[q] = col + 2; }
        if (v[p].w != 0.f) { int q = atomicAdd(&s_cnt, 1); if (q < MAXDEG) s_idx[q] = col + 3; }
    }
    __syncthreads();
    int cnt = s_cnt; if (cnt > MAXDEG) cnt = MAXDEG;   // deg>=1 (self-loop)
    if (t < cnt) nbr[(size_t)i * MAXDEG + t] = s_idx[t];
    if (t == 0) deg[i] = cnt;
    const float inv = 1.0f / (float)cnt;
    const int col = t & 127;
    const int g = t >> 7;
    float acc = 0.f;
    for (int k = g; k < cnt; k += 2)
        acc += X[(size_t)s_idx[k] * 256 + 128 + col];
    s_part[g][col] = acc;
    __syncthreads();
    float vv = 0.f;
    if (t < 128) {
        float tot = s_part[0][t] + s_part[1][t];
        vv = X[(size_t)i * 256 + t] + tot * inv + b1[t];
        vv = fmaxf(vv, 0.f);
        float s = vv * vv;
#pragma unroll
        for (int off = 32; off > 0; off >>= 1) s += __shfl_down(s, off, 64);
        if ((t & 63) == 0) s_w[t >> 6] = s;
    }
    __syncthreads();
    if (t < 128) {
        float denom = fmaxf(sqrtf(s_w[0] + s_w[1]), 1e-12f);
        H1b[(size_t)i * 128 + t] = f2bf(vv / denom);
    }
}

// ---------------------------------------------------------------------------
// Layer-2 + head fused, per batch node b (128 threads). Cached CSR.
// Y[i][0:128]=Ya, Y[i][128:256]=Yb (fp32).
// ---------------------------------------------------------------------------
__global__ __launch_bounds__(128) void k_l2head(const int* __restrict__ nodes,
                                                const int* __restrict__ nbr,
                                                const int* __restrict__ deg,
                                                const float* __restrict__ Y,
                                                const float* __restrict__ b2,
                                                const float* __restrict__ Wl1t,
                                                const float* __restrict__ bl1,
                                                const float* __restrict__ Wl2,
                                                const float* __restrict__ bl2,
                                                float* __restrict__ out) {
    const int b = blockIdx.x;
    const int t = threadIdx.x;
    const int n = nodes[b];
    const int cnt = deg[n];
    __shared__ int s_idx[MAXDEG];
    __shared__ float s_h[128];
    __shared__ float s_x[128];
    __shared__ float s_c[C_DIM];
    __shared__ float s_w[2];
    if (t < cnt) s_idx[t] = nbr[(size_t)n * MAXDEG + t];
    __syncthreads();
    float a0 = 0.f, a1 = 0.f;
    int k = 0;
    for (; k + 1 < cnt; k += 2) {
        a0 += Y[(size_t)s_idx[k]     * 256 + 128 + t];
        a1 += Y[(size_t)s_idx[k + 1] * 256 + 128 + t];
    }
    if (k < cnt) a0 += Y[(size_t)s_idx[k] * 256 + 128 + t];
    float vv = Y[(size_t)n * 256 + t] + (a0 + a1) / (float)cnt + b2[t];
    vv = fmaxf(vv, 0.f);
    float s = vv * vv;
#pragma unroll
    for (int off = 32; off > 0; off >>= 1) s += __shfl_down(s, off, 64);
    if ((t & 63) == 0) s_w[t >> 6] = s;
    __syncthreads();
    float denom = fmaxf(sqrtf(s_w[0] + s_w[1]), 1e-12f);
    s_h[t] = vv / denom;
    __syncthreads();
    float x1 = bl1[t];
#pragma unroll 8
    for (int kk = 0; kk < 128; ++kk)
        x1 += Wl1t[kk * 128 + t] * s_h[kk];
    s_x[t] = x1;
    __syncthreads();
    if (t < C_DIM) {
        float l = bl2[t];
        const float* wr = Wl2 + (size_t)t * 128;
        for (int kk = 0; kk < 128; ++kk) l += wr[kk] * s_x[kk];
        s_c[t] = l;
    }
    __syncthreads();
    if (t < C_DIM) {
        float mx = -1e30f;
        for (int c = 0; c < C_DIM; ++c) mx = fmaxf(mx, s_c[c]);
        float se = 0.f;
        for (int c = 0; c < C_DIM; ++c) se += expf(s_c[c] - mx);
        out[(size_t)b * C_DIM + t] = expf(s_c[t] - mx) / se;
    }
}

// ---------------------------------------------------------------------------
// Launch
// ---------------------------------------------------------------------------
extern "C" void kernel_launch(void* const* d_in, const int* in_sizes, int n_in,
                              void* d_out, int out_size, void* d_ws, size_t ws_size,
                              hipStream_t stream) {
    const int*   nodes = (const int*)  d_in[0];
    const float* adj   = (const float*)d_in[1];
    const float* data  = (const float*)d_in[2];
    const float* W1    = (const float*)d_in[3];
    const float* b1    = (const float*)d_in[4];
    const float* W2    = (const float*)d_in[5];
    const float* b2    = (const float*)d_in[6];
    const float* Wl1   = (const float*)d_in[7];
    const float* bl1   = (const float*)d_in[8];
    const float* Wl2   = (const float*)d_in[9];
    const float* bl2   = (const float*)d_in[10];
    float* out = (float*)d_out;

    // workspace layout (all 16B-aligned)
    unsigned short* Ab  = (unsigned short*)d_ws;            // 16384*512 bf16
    unsigned short* Wt1 = Ab  + (size_t)N_NODES * KP1;      // 256*512
    unsigned short* Wt2 = Wt1 + 256 * KP1;                  // 256*128
    unsigned short* H1b = Wt2 + 256 * 128;                  // 16384*128
    float* Wl1t = (float*)(H1b + (size_t)N_NODES * 128);    // 128*128
    float* X    = Wl1t + 128 * 128;                         // 16384*256
    float* Y    = X    + (size_t)N_NODES * 256;             // 16384*256
    int*   nbr  = (int*)(Y + (size_t)N_NODES * 256);        // 16384*128
    int*   deg  = nbr + (size_t)N_NODES * MAXDEG;           // 16384

    // prep: casts + transposes
    k_cast_data<<<N_NODES, 256, 0, stream>>>(data, Ab);
    k_prep_w1b <<<512, 256, 0, stream>>>(W1, Wt1);
    k_prep_w2b <<<128, 256, 0, stream>>>(W2, Wt2);
    k_tp<<<dim3(4, 4), dim3(32, 8), 0, stream>>>(Wl1, Wl1t);

    // layer 1: MFMA GEMM (agg-after-GEMM via linearity), then fused scan+agg+norm
    k_gemm_mfma<<<N_NODES / 32, 256, 0, stream>>>(Ab, Wt1, KP1, X);
    k_agg1     <<<N_NODES, 256, 0, stream>>>(adj, X, b1, H1b, nbr, deg);

    // layer 2: MFMA GEMM on all nodes, then fused agg+norm+head per batch node
    k_gemm_mfma<<<N_NODES / 32, 256, 0, stream>>>(H1b, Wt2, E_DIM, Y);
    k_l2head   <<<B_DIM, 128, 0, stream>>>(nodes, nbr, deg, Y, b2, Wl1t, bl1, Wl2, bl2, out);
}

// Round 5
// 1424.349 us; speedup vs baseline: 1.3157x; 1.0134x over previous
//
#include <hip/hip_runtime.h>
#include <math.h>
#include <stddef.h>

#define N_NODES 16384
#define F_DIM   500
#define KP1     512
#define E_DIM   128
#define C_DIM   10
#define B_DIM   4096
#define MAXDEG  128

typedef __attribute__((ext_vector_type(8))) short short8;   // 8 bf16 = 4 VGPRs
typedef __attribute__((ext_vector_type(4))) float f32x4;    // MFMA C/D

__device__ inline unsigned short f2bf(float f) {
    union { float f; unsigned int u; } v; v.f = f;
    unsigned int u = v.u;
    u += 0x7FFFu + ((u >> 16) & 1u);        // RNE
    return (unsigned short)(u >> 16);
}

// Wt1 [256][512] bf16: row n<128 -> W1[n][0:500]; n>=128 -> W1[n-128][500:1000]
__global__ __launch_bounds__(256) void k_prep_w1b(const float* __restrict__ W1,
                                                  unsigned short* __restrict__ Wt) {
    int idx = blockIdx.x * 256 + threadIdx.x;     // 256*512
    int n = idx >> 9, k = idx & 511;
    float v = (k < F_DIM) ? W1[(size_t)(n & 127) * 1000 + (n >> 7) * F_DIM + k] : 0.0f;
    Wt[idx] = f2bf(v);
}

// Wt2 [256][128] bf16: row n<128 -> W2[n][0:128]; n>=128 -> W2[n-128][128:256]
__global__ __launch_bounds__(256) void k_prep_w2b(const float* __restrict__ W2,
                                                  unsigned short* __restrict__ Wt) {
    int idx = blockIdx.x * 256 + threadIdx.x;     // 256*128
    int n = idx >> 7, k = idx & 127;
    Wt[idx] = f2bf(W2[(size_t)(n & 127) * 256 + (n >> 7) * 128 + k]);
}

// Wl1t[k][e] = Wl1[e][k]  (128x128 fp32, tiled transpose)
__global__ void k_tp(const float* __restrict__ src, float* __restrict__ dst) {
    __shared__ float tile[32][33];
    const int k0 = blockIdx.x * 32;
    const int e0 = blockIdx.y * 32;
    const int tx = threadIdx.x, ty0 = threadIdx.y;
#pragma unroll
    for (int q = 0; q < 4; ++q) {
        int ty = ty0 + q * 8;
        tile[ty][tx] = src[(size_t)(e0 + ty) * 128 + k0 + tx];
    }
    __syncthreads();
#pragma unroll
    for (int q = 0; q < 4; ++q) {
        int ty = ty0 + q * 8;
        dst[(size_t)(k0 + ty) * 128 + e0 + tx] = tile[tx][ty];
    }
}

// ---------------------------------------------------------------------------
// MFMA bf16 GEMM: Cout[M][256] = A[M][Ka] @ B^T[256][Kpad], fp32 out.
// A is fp32 (a_fp32=1, inline RNE cast during staging) or bf16 (a_fp32=0).
// Ka = real A row stride; Kpad = padded K (mult of 32) = B row stride.
// Tile 32x256, 256 thr (4 waves); wave w covers cols w*64..w*64+63.
// Per wave: 2 m-tiles x 4 n-tiles of 16x16 via v_mfma_f32_16x16x32_bf16.
// LDS rows padded to 40 bf16 (20-word stride -> <=2-way bank aliasing, free).
// ---------------------------------------------------------------------------
__global__ __launch_bounds__(256) void k_gemm_mfma(const void* __restrict__ Ap,
                                                   int Ka, int Kpad, int a_fp32,
                                                   const unsigned short* __restrict__ B,
                                                   float* __restrict__ Cout) {
    __shared__ unsigned short sA[32 * 40];
    __shared__ unsigned short sB[256 * 40];
    const int tid  = threadIdx.x;
    const int w    = tid >> 6;
    const int lane = tid & 63;
    const int l16  = lane & 15;
    const int quad = lane >> 4;
    const int blockM = blockIdx.x * 32;
    f32x4 acc[2][4] = {};
    const int nchunks = Kpad >> 5;

    for (int c = 0; c < nchunks; ++c) {
        const int k0 = c << 5;
        if (tid < 128) {                       // A tile: 32 rows x 32 bf16
            int row = tid >> 2, cc = tid & 3;
            int kbase = k0 + cc * 8;
            short8 v;
            if (a_fp32) {
                const float* Arow = (const float*)Ap + (size_t)(blockM + row) * Ka;
                float4 f0 = (kbase + 4 <= Ka) ? *(const float4*)(Arow + kbase)
                                              : make_float4(0.f, 0.f, 0.f, 0.f);
                float4 f1 = (kbase + 8 <= Ka) ? *(const float4*)(Arow + kbase + 4)
                                              : make_float4(0.f, 0.f, 0.f, 0.f);
                v[0] = (short)f2bf(f0.x); v[1] = (short)f2bf(f0.y);
                v[2] = (short)f2bf(f0.z); v[3] = (short)f2bf(f0.w);
                v[4] = (short)f2bf(f1.x); v[5] = (short)f2bf(f1.y);
                v[6] = (short)f2bf(f1.z); v[7] = (short)f2bf(f1.w);
            } else {
                v = *(const short8*)((const unsigned short*)Ap +
                                     (size_t)(blockM + row) * Ka + kbase);
            }
            *(short8*)(sA + row * 40 + cc * 8) = v;
        }
#pragma unroll
        for (int q = 0; q < 4; ++q) {          // B tile: 256 rows x 32 bf16
            int idx = tid + 256 * q;
            int row = idx >> 2, cc = idx & 3;
            short8 v = *(const short8*)(B + (size_t)row * Kpad + k0 + cc * 8);
            *(short8*)(sB + row * 40 + cc * 8) = v;
        }
        __syncthreads();
        short8 af[2], bf[4];
#pragma unroll
        for (int mt = 0; mt < 2; ++mt)
            af[mt] = *(const short8*)(sA + (mt * 16 + l16) * 40 + quad * 8);
#pragma unroll
        for (int nt = 0; nt < 4; ++nt)
            bf[nt] = *(const short8*)(sB + (w * 64 + nt * 16 + l16) * 40 + quad * 8);
#pragma unroll
        for (int mt = 0; mt < 2; ++mt)
#pragma unroll
            for (int nt = 0; nt < 4; ++nt)
                acc[mt][nt] = __builtin_amdgcn_mfma_f32_16x16x32_bf16(af[mt], bf[nt], acc[mt][nt], 0, 0, 0);
        __syncthreads();
    }
    // C/D layout: col = lane&15, row = quad*4 + reg   [verified m89/m91]
#pragma unroll
    for (int mt = 0; mt < 2; ++mt)
#pragma unroll
        for (int nt = 0; nt < 4; ++nt) {
            int col = w * 64 + nt * 16 + l16;
#pragma unroll
            for (int r = 0; r < 4; ++r) {
                int row = blockM + mt * 16 + quad * 4 + r;
                Cout[(size_t)row * 256 + col] = acc[mt][nt][r];
            }
        }
}

// ---------------------------------------------------------------------------
// Layer-1 fused: scan adj row (16 float4/thread prefetch), cache CSR,
// 8-way neighbor-parallel float4 gather of Xb, relu+l2norm, emit bf16 H1.
// X: [i][0:128]=Xa=data@W1a^T, [i][128:256]=Xb=data@W1b^T (fp32).
// ---------------------------------------------------------------------------
__global__ __launch_bounds__(256) void k_agg1(const float* __restrict__ adj,
                                              const float* __restrict__ X,
                                              const float* __restrict__ b1,
                                              unsigned short* __restrict__ H1b,
                                              int* __restrict__ nbr,
                                              int* __restrict__ deg) {
    const int i = blockIdx.x;
    const int t = threadIdx.x;
    const float4* row4 = (const float4*)(adj + (size_t)i * N_NODES);
    __shared__ int s_cnt;
    __shared__ int s_idx[MAXDEG];
    __shared__ float s_part[8][128];
    __shared__ float s_w[2];
    if (t == 0) s_cnt = 0;
    __syncthreads();
    float4 v[16];
#pragma unroll
    for (int p = 0; p < 16; ++p) v[p] = row4[p * 256 + t];
#pragma unroll
    for (int p = 0; p < 16; ++p) {
        int col = p * 1024 + t * 4;
        if (v[p].x != 0.f) { int q = atomicAdd(&s_cnt, 1); if (q < MAXDEG) s_idx[q] = col;     }
        if (v[p].y != 0.f) { int q = atomicAdd(&s_cnt, 1); if (q < MAXDEG) s_idx[q] = col + 1; }
        if (v[p].z != 0.f) { int q = atomicAdd(&s_cnt, 1); if (q < MAXDEG) s_idx[q] = col + 2; }
        if (v[p].w != 0.f) { int q = atomicAdd(&s_cnt, 1); if (q < MAXDEG) s_idx[q] = col + 3; }
    }
    __syncthreads();
    int cnt = s_cnt; if (cnt > MAXDEG) cnt = MAXDEG;   // deg>=1 (self-loop)
    if (t < cnt) nbr[(size_t)i * MAXDEG + t] = s_idx[t];
    if (t == 0) deg[i] = cnt;
    const float inv = 1.0f / (float)cnt;
    // 8-way neighbor-parallel gather: group g (32 lanes) does k = g, g+8, ...
    const int g = t >> 5, l = t & 31;
    float4 a4 = make_float4(0.f, 0.f, 0.f, 0.f);
    for (int k = g; k < cnt; k += 8) {
        float4 x4 = ((const float4*)(X + (size_t)s_idx[k] * 256 + 128))[l];
        a4.x += x4.x; a4.y += x4.y; a4.z += x4.z; a4.w += x4.w;
    }
    *(float4*)&s_part[g][l * 4] = a4;
    __syncthreads();
    float vv = 0.f;
    if (t < 128) {
        float tot = 0.f;
#pragma unroll
        for (int g2 = 0; g2 < 8; ++g2) tot += s_part[g2][t];
        vv = X[(size_t)i * 256 + t] + tot * inv + b1[t];
        vv = fmaxf(vv, 0.f);
        float s = vv * vv;
#pragma unroll
        for (int off = 32; off > 0; off >>= 1) s += __shfl_down(s, off, 64);
        if ((t & 63) == 0) s_w[t >> 6] = s;
    }
    __syncthreads();
    if (t < 128) {
        float denom = fmaxf(sqrtf(s_w[0] + s_w[1]), 1e-12f);
        H1b[(size_t)i * 128 + t] = f2bf(vv / denom);
    }
}

// ---------------------------------------------------------------------------
// Layer-2 + head fused, per batch node b (256 threads). Cached CSR — zero
// adj bytes. Y[i][0:128]=Ya, [i][128:256]=Yb (fp32). 8-way float4 gather.
// ---------------------------------------------------------------------------
__global__ __launch_bounds__(256) void k_l2head(const int* __restrict__ nodes,
                                                const int* __restrict__ nbr,
                                                const int* __restrict__ deg,
                                                const float* __restrict__ Y,
                                                const float* __restrict__ b2,
                                                const float* __restrict__ Wl1t,
                                                const float* __restrict__ bl1,
                                                const float* __restrict__ Wl2,
                                                const float* __restrict__ bl2,
                                                float* __restrict__ out) {
    const int b = blockIdx.x;
    const int t = threadIdx.x;
    const int n = nodes[b];
    const int cnt = deg[n];
    __shared__ int s_idx[MAXDEG];
    __shared__ float s_part[8][128];
    __shared__ float s_h[128];
    __shared__ float s_x[128];
    __shared__ float s_c[C_DIM];
    __shared__ float s_w[2];
    if (t < cnt) s_idx[t] = nbr[(size_t)n * MAXDEG + t];
    __syncthreads();
    const int g = t >> 5, l = t & 31;
    float4 a4 = make_float4(0.f, 0.f, 0.f, 0.f);
    for (int k = g; k < cnt; k += 8) {
        float4 y4 = ((const float4*)(Y + (size_t)s_idx[k] * 256 + 128))[l];
        a4.x += y4.x; a4.y += y4.y; a4.z += y4.z; a4.w += y4.w;
    }
    *(float4*)&s_part[g][l * 4] = a4;
    __syncthreads();
    if (t < 128) {
        float tot = 0.f;
#pragma unroll
        for (int g2 = 0; g2 < 8; ++g2) tot += s_part[g2][t];
        float vv = Y[(size_t)n * 256 + t] + tot / (float)cnt + b2[t];
        vv = fmaxf(vv, 0.f);
        float s = vv * vv;
#pragma unroll
        for (int off = 32; off > 0; off >>= 1) s += __shfl_down(s, off, 64);
        if ((t & 63) == 0) s_w[t >> 6] = s;
        __syncthreads();
        float denom = fmaxf(sqrtf(s_w[0] + s_w[1]), 1e-12f);
        s_h[t] = vv / denom;
    } else {
        __syncthreads();
    }
    __syncthreads();
    if (t < 128) {
        float x1 = bl1[t];
#pragma unroll 8
        for (int kk = 0; kk < 128; ++kk)
            x1 += Wl1t[kk * 128 + t] * s_h[kk];
        s_x[t] = x1;
    }
    __syncthreads();
    if (t < C_DIM) {
        float l2 = bl2[t];
        const float* wr = Wl2 + (size_t)t * 128;
        for (int kk = 0; kk < 128; ++kk) l2 += wr[kk] * s_x[kk];
        s_c[t] = l2;
    }
    __syncthreads();
    if (t < C_DIM) {
        float mx = -1e30f;
        for (int c = 0; c < C_DIM; ++c) mx = fmaxf(mx, s_c[c]);
        float se = 0.f;
        for (int c = 0; c < C_DIM; ++c) se += expf(s_c[c] - mx);
        out[(size_t)b * C_DIM + t] = expf(s_c[t] - mx) / se;
    }
}

// ---------------------------------------------------------------------------
// Launch
// ---------------------------------------------------------------------------
extern "C" void kernel_launch(void* const* d_in, const int* in_sizes, int n_in,
                              void* d_out, int out_size, void* d_ws, size_t ws_size,
                              hipStream_t stream) {
    const int*   nodes = (const int*)  d_in[0];
    const float* adj   = (const float*)d_in[1];
    const float* data  = (const float*)d_in[2];
    const float* W1    = (const float*)d_in[3];
    const float* b1    = (const float*)d_in[4];
    const float* W2    = (const float*)d_in[5];
    const float* b2    = (const float*)d_in[6];
    const float* Wl1   = (const float*)d_in[7];
    const float* bl1   = (const float*)d_in[8];
    const float* Wl2   = (const float*)d_in[9];
    const float* bl2   = (const float*)d_in[10];
    float* out = (float*)d_out;

    // workspace layout (all 16B-aligned)
    unsigned short* Wt1 = (unsigned short*)d_ws;            // 256*512 bf16
    unsigned short* Wt2 = Wt1 + 256 * KP1;                  // 256*128
    unsigned short* H1b = Wt2 + 256 * 128;                  // 16384*128
    float* Wl1t = (float*)(H1b + (size_t)N_NODES * 128);    // 128*128
    float* X    = Wl1t + 128 * 128;                         // 16384*256
    float* Y    = X    + (size_t)N_NODES * 256;             // 16384*256
    int*   nbr  = (int*)(Y + (size_t)N_NODES * 256);        // 16384*128
    int*   deg  = nbr + (size_t)N_NODES * MAXDEG;           // 16384

    // weight prep
    k_prep_w1b <<<512, 256, 0, stream>>>(W1, Wt1);
    k_prep_w2b <<<128, 256, 0, stream>>>(W2, Wt2);
    k_tp<<<dim3(4, 4), dim3(32, 8), 0, stream>>>(Wl1, Wl1t);

    // layer 1: MFMA GEMM (inline fp32->bf16 A-cast), then fused scan+agg+norm
    k_gemm_mfma<<<N_NODES / 32, 256, 0, stream>>>(data, F_DIM, KP1, 1, Wt1, X);
    k_agg1     <<<N_NODES, 256, 0, stream>>>(adj, X, b1, H1b, nbr, deg);

    // layer 2: MFMA GEMM on all nodes, then fused agg+norm+head per batch node
    k_gemm_mfma<<<N_NODES / 32, 256, 0, stream>>>(H1b, E_DIM, E_DIM, 0, Wt2, Y);
    k_l2head   <<<B_DIM, 256, 0, stream>>>(nodes, nbr, deg, Y, b2, Wl1t, bl1, Wl2, bl2, out);
}

// Round 6
// 1422.823 us; speedup vs baseline: 1.3172x; 1.0011x over previous
//
#include <hip/hip_runtime.h>
#include <math.h>
#include <stddef.h>

#define N_NODES 16384
#define F_DIM   500
#define KP1     512
#define E_DIM   128
#define C_DIM   10
#define B_DIM   4096
#define MAXDEG  128

typedef __attribute__((ext_vector_type(8))) short short8;   // 8 bf16 = 4 VGPRs
typedef __attribute__((ext_vector_type(4))) float f32x4;    // MFMA C/D

__device__ inline unsigned short f2bf(float f) {
    union { float f; unsigned int u; } v; v.f = f;
    unsigned int u = v.u;
    u += 0x7FFFu + ((u >> 16) & 1u);        // RNE
    return (unsigned short)(u >> 16);
}

// ---------------------------------------------------------------------------
// Merged weight prep (block-ranged):
//  blocks [0,512):  Wt1 [256][512] bf16  (W1 rows split at col 500)
//  blocks [512,640): Wt2 [256][128] bf16 (W2 rows split at col 128)
//  blocks [640,656): Wl1t[k][e] = Wl1[e][k] (fp32 tiled transpose, 32x32)
// ---------------------------------------------------------------------------
__global__ __launch_bounds__(256) void k_prep(const float* __restrict__ W1,
                                              const float* __restrict__ W2,
                                              const float* __restrict__ Wl1,
                                              unsigned short* __restrict__ Wt1,
                                              unsigned short* __restrict__ Wt2,
                                              float* __restrict__ Wl1t) {
    const int bb = blockIdx.x;
    const int t = threadIdx.x;
    if (bb < 512) {
        int idx = bb * 256 + t;                   // 256*512
        int n = idx >> 9, k = idx & 511;
        float v = (k < F_DIM) ? W1[(size_t)(n & 127) * 1000 + (n >> 7) * F_DIM + k] : 0.0f;
        Wt1[idx] = f2bf(v);
    } else if (bb < 640) {
        int idx = (bb - 512) * 256 + t;           // 256*128
        int n = idx >> 7, k = idx & 127;
        Wt2[idx] = f2bf(W2[(size_t)(n & 127) * 256 + (n >> 7) * 128 + k]);
    } else {
        __shared__ float tile[32][33];
        int tb = bb - 640;                        // 16 tiles (4x4)
        int k0 = (tb & 3) * 32, e0 = (tb >> 2) * 32;
        int tx = t & 31, ty0 = t >> 5;            // ty0 0..7
#pragma unroll
        for (int q = 0; q < 4; ++q) {
            int ty = ty0 + q * 8;
            tile[ty][tx] = Wl1[(size_t)(e0 + ty) * 128 + k0 + tx];
        }
        __syncthreads();
#pragma unroll
        for (int q = 0; q < 4; ++q) {
            int ty = ty0 + q * 8;
            Wl1t[(size_t)(k0 + ty) * 128 + e0 + tx] = tile[tx][ty];
        }
    }
}

// ---------------------------------------------------------------------------
// k_mix (block-ranged, independent work co-scheduled):
//  blocks [0,512):      GEMM1  X[32-row tile][256] = data(fp32->bf16) @ Wt1^T
//  blocks [512,16896):  adj-row scan -> CSR (nbr ushort, deg int)
// GEMM compute hides inside the scan's HBM-bound stream.
// ---------------------------------------------------------------------------
__global__ __launch_bounds__(256) void k_mix(const float* __restrict__ data,
                                             const unsigned short* __restrict__ Wt1,
                                             float* __restrict__ X,
                                             const float* __restrict__ adj,
                                             unsigned short* __restrict__ nbr,
                                             int* __restrict__ deg) {
    __shared__ alignas(16) unsigned char s_raw[(32 * 40 + 256 * 40) * 2];
    const int bb = blockIdx.x;
    const int tid = threadIdx.x;

    if (bb < 512) {
        // ---------------- GEMM1 path ----------------
        unsigned short* sA = (unsigned short*)s_raw;          // 32 x 40
        unsigned short* sB = sA + 32 * 40;                    // 256 x 40
        const int w    = tid >> 6;
        const int lane = tid & 63;
        const int l16  = lane & 15;
        const int quad = lane >> 4;
        const int blockM = bb * 32;
        f32x4 acc[2][4] = {};
#pragma unroll 1
        for (int c = 0; c < (KP1 >> 5); ++c) {
            const int k0 = c << 5;
            if (tid < 128) {                  // A tile: 32 rows x 32 (fp32->bf16)
                int row = tid >> 2, cc = tid & 3;
                int kbase = k0 + cc * 8;
                const float* Arow = data + (size_t)(blockM + row) * F_DIM;
                float4 f0 = (kbase + 4 <= F_DIM) ? *(const float4*)(Arow + kbase)
                                                 : make_float4(0.f, 0.f, 0.f, 0.f);
                float4 f1 = (kbase + 8 <= F_DIM) ? *(const float4*)(Arow + kbase + 4)
                                                 : make_float4(0.f, 0.f, 0.f, 0.f);
                short8 v;
                v[0] = (short)f2bf(f0.x); v[1] = (short)f2bf(f0.y);
                v[2] = (short)f2bf(f0.z); v[3] = (short)f2bf(f0.w);
                v[4] = (short)f2bf(f1.x); v[5] = (short)f2bf(f1.y);
                v[6] = (short)f2bf(f1.z); v[7] = (short)f2bf(f1.w);
                *(short8*)(sA + row * 40 + cc * 8) = v;
            }
#pragma unroll
            for (int q = 0; q < 4; ++q) {     // B tile: 256 rows x 32 bf16
                int idx = tid + 256 * q;
                int row = idx >> 2, cc = idx & 3;
                short8 v = *(const short8*)(Wt1 + (size_t)row * KP1 + k0 + cc * 8);
                *(short8*)(sB + row * 40 + cc * 8) = v;
            }
            __syncthreads();
            short8 af[2], bf[4];
#pragma unroll
            for (int mt = 0; mt < 2; ++mt)
                af[mt] = *(const short8*)(sA + (mt * 16 + l16) * 40 + quad * 8);
#pragma unroll
            for (int nt = 0; nt < 4; ++nt)
                bf[nt] = *(const short8*)(sB + (w * 64 + nt * 16 + l16) * 40 + quad * 8);
#pragma unroll
            for (int mt = 0; mt < 2; ++mt)
#pragma unroll
                for (int nt = 0; nt < 4; ++nt)
                    acc[mt][nt] = __builtin_amdgcn_mfma_f32_16x16x32_bf16(af[mt], bf[nt], acc[mt][nt], 0, 0, 0);
            __syncthreads();
        }
        // C/D layout: col = lane&15, row = quad*4 + reg   [verified m89/m91]
#pragma unroll
        for (int mt = 0; mt < 2; ++mt)
#pragma unroll
            for (int nt = 0; nt < 4; ++nt) {
                int col = w * 64 + nt * 16 + l16;
#pragma unroll
                for (int r = 0; r < 4; ++r) {
                    int row = blockM + mt * 16 + quad * 4 + r;
                    X[(size_t)row * 256 + col] = acc[mt][nt][r];
                }
            }
    } else {
        // ---------------- adj scan path ----------------
        const int i = bb - 512;
        int* s_cnt = (int*)s_raw;
        int* s_idx = ((int*)s_raw) + 4;       // offset 16 B
        const float4* row4 = (const float4*)(adj + (size_t)i * N_NODES);
        if (tid == 0) *s_cnt = 0;
        __syncthreads();
        float4 v[16];
#pragma unroll
        for (int p = 0; p < 16; ++p) v[p] = row4[p * 256 + tid];
#pragma unroll
        for (int p = 0; p < 16; ++p) {
            int col = p * 1024 + tid * 4;
            if (v[p].x != 0.f) { int q = atomicAdd(s_cnt, 1); if (q < MAXDEG) s_idx[q] = col;     }
            if (v[p].y != 0.f) { int q = atomicAdd(s_cnt, 1); if (q < MAXDEG) s_idx[q] = col + 1; }
            if (v[p].z != 0.f) { int q = atomicAdd(s_cnt, 1); if (q < MAXDEG) s_idx[q] = col + 2; }
            if (v[p].w != 0.f) { int q = atomicAdd(s_cnt, 1); if (q < MAXDEG) s_idx[q] = col + 3; }
        }
        __syncthreads();
        int cnt = *s_cnt; if (cnt > MAXDEG) cnt = MAXDEG;   // deg>=1 (self-loop)
        if (tid < cnt) nbr[(size_t)i * MAXDEG + tid] = (unsigned short)s_idx[tid];
        if (tid == 0) deg[i] = cnt;
    }
}

// ---------------------------------------------------------------------------
// Gather + relu + l2norm for layer 1: one 256-thr block per node.
// H1b[i] = bf16( l2norm(relu(Xa[i] + mean_j Xb[j] + b1)) )
// X: [i][0:128]=Xa, [i][128:256]=Xb (fp32). 8-way neighbor-parallel float4.
// ---------------------------------------------------------------------------
__global__ __launch_bounds__(256) void k_gather(const unsigned short* __restrict__ nbr,
                                                const int* __restrict__ deg,
                                                const float* __restrict__ X,
                                                const float* __restrict__ b1,
                                                unsigned short* __restrict__ H1b) {
    const int i = blockIdx.x;
    const int t = threadIdx.x;
    const int cnt = deg[i];
    __shared__ int s_idx[MAXDEG];
    __shared__ float s_part[8][128];
    __shared__ float s_w[2];
    if (t < cnt) s_idx[t] = nbr[(size_t)i * MAXDEG + t];
    __syncthreads();
    const int g = t >> 5, l = t & 31;
    float4 a4 = make_float4(0.f, 0.f, 0.f, 0.f);
    for (int k = g; k < cnt; k += 8) {
        float4 x4 = ((const float4*)(X + (size_t)s_idx[k] * 256 + 128))[l];
        a4.x += x4.x; a4.y += x4.y; a4.z += x4.z; a4.w += x4.w;
    }
    *(float4*)&s_part[g][l * 4] = a4;
    __syncthreads();
    float vv = 0.f;
    if (t < 128) {
        float tot = 0.f;
#pragma unroll
        for (int g2 = 0; g2 < 8; ++g2) tot += s_part[g2][t];
        vv = X[(size_t)i * 256 + t] + tot / (float)cnt + b1[t];
        vv = fmaxf(vv, 0.f);
        float s = vv * vv;
#pragma unroll
        for (int off = 32; off > 0; off >>= 1) s += __shfl_down(s, off, 64);
        if ((t & 63) == 0) s_w[t >> 6] = s;
    }
    __syncthreads();
    if (t < 128) {
        float denom = fmaxf(sqrtf(s_w[0] + s_w[1]), 1e-12f);
        H1b[(size_t)i * 128 + t] = f2bf(vv / denom);
    }
}

// ---------------------------------------------------------------------------
// MFMA bf16 GEMM (bf16 A): Y[M][256] = A[M][K] @ B^T[256][K], fp32 out.
// Used for layer 2 (K=128). Same tile/layout as k_mix's GEMM path.
// ---------------------------------------------------------------------------
__global__ __launch_bounds__(256) void k_gemm_mfma(const unsigned short* __restrict__ A,
                                                   int K,
                                                   const unsigned short* __restrict__ B,
                                                   float* __restrict__ Cout) {
    __shared__ unsigned short sA[32 * 40];
    __shared__ unsigned short sB[256 * 40];
    const int tid  = threadIdx.x;
    const int w    = tid >> 6;
    const int lane = tid & 63;
    const int l16  = lane & 15;
    const int quad = lane >> 4;
    const int blockM = blockIdx.x * 32;
    f32x4 acc[2][4] = {};
    for (int c = 0; c < (K >> 5); ++c) {
        const int k0 = c << 5;
        if (tid < 128) {
            int row = tid >> 2, cc = tid & 3;
            short8 v = *(const short8*)(A + (size_t)(blockM + row) * K + k0 + cc * 8);
            *(short8*)(sA + row * 40 + cc * 8) = v;
        }
#pragma unroll
        for (int q = 0; q < 4; ++q) {
            int idx = tid + 256 * q;
            int row = idx >> 2, cc = idx & 3;
            short8 v = *(const short8*)(B + (size_t)row * K + k0 + cc * 8);
            *(short8*)(sB + row * 40 + cc * 8) = v;
        }
        __syncthreads();
        short8 af[2], bf[4];
#pragma unroll
        for (int mt = 0; mt < 2; ++mt)
            af[mt] = *(const short8*)(sA + (mt * 16 + l16) * 40 + quad * 8);
#pragma unroll
        for (int nt = 0; nt < 4; ++nt)
            bf[nt] = *(const short8*)(sB + (w * 64 + nt * 16 + l16) * 40 + quad * 8);
#pragma unroll
        for (int mt = 0; mt < 2; ++mt)
#pragma unroll
            for (int nt = 0; nt < 4; ++nt)
                acc[mt][nt] = __builtin_amdgcn_mfma_f32_16x16x32_bf16(af[mt], bf[nt], acc[mt][nt], 0, 0, 0);
        __syncthreads();
    }
#pragma unroll
    for (int mt = 0; mt < 2; ++mt)
#pragma unroll
        for (int nt = 0; nt < 4; ++nt) {
            int col = w * 64 + nt * 16 + l16;
#pragma unroll
            for (int r = 0; r < 4; ++r) {
                int row = blockM + mt * 16 + quad * 4 + r;
                Cout[(size_t)row * 256 + col] = acc[mt][nt][r];
            }
        }
}

// ---------------------------------------------------------------------------
// Layer-2 + head fused, per batch node b (256 threads). Cached CSR (ushort).
// Y[i][0:128]=Ya, [i][128:256]=Yb (fp32). 8-way float4 gather.
// ---------------------------------------------------------------------------
__global__ __launch_bounds__(256) void k_l2head(const int* __restrict__ nodes,
                                                const unsigned short* __restrict__ nbr,
                                                const int* __restrict__ deg,
                                                const float* __restrict__ Y,
                                                const float* __restrict__ b2,
                                                const float* __restrict__ Wl1t,
                                                const float* __restrict__ bl1,
                                                const float* __restrict__ Wl2,
                                                const float* __restrict__ bl2,
                                                float* __restrict__ out) {
    const int b = blockIdx.x;
    const int t = threadIdx.x;
    const int n = nodes[b];
    const int cnt = deg[n];
    __shared__ int s_idx[MAXDEG];
    __shared__ float s_part[8][128];
    __shared__ float s_h[128];
    __shared__ float s_x[128];
    __shared__ float s_c[C_DIM];
    __shared__ float s_w[2];
    if (t < cnt) s_idx[t] = nbr[(size_t)n * MAXDEG + t];
    __syncthreads();
    const int g = t >> 5, l = t & 31;
    float4 a4 = make_float4(0.f, 0.f, 0.f, 0.f);
    for (int k = g; k < cnt; k += 8) {
        float4 y4 = ((const float4*)(Y + (size_t)s_idx[k] * 256 + 128))[l];
        a4.x += y4.x; a4.y += y4.y; a4.z += y4.z; a4.w += y4.w;
    }
    *(float4*)&s_part[g][l * 4] = a4;
    __syncthreads();
    if (t < 128) {
        float tot = 0.f;
#pragma unroll
        for (int g2 = 0; g2 < 8; ++g2) tot += s_part[g2][t];
        float vv = Y[(size_t)n * 256 + t] + tot / (float)cnt + b2[t];
        vv = fmaxf(vv, 0.f);
        float s = vv * vv;
#pragma unroll
        for (int off = 32; off > 0; off >>= 1) s += __shfl_down(s, off, 64);
        if ((t & 63) == 0) s_w[t >> 6] = s;
        __syncthreads();
        float denom = fmaxf(sqrtf(s_w[0] + s_w[1]), 1e-12f);
        s_h[t] = vv / denom;
    } else {
        __syncthreads();
    }
    __syncthreads();
    if (t < 128) {
        float x1 = bl1[t];
#pragma unroll 8
        for (int kk = 0; kk < 128; ++kk)
            x1 += Wl1t[kk * 128 + t] * s_h[kk];
        s_x[t] = x1;
    }
    __syncthreads();
    if (t < C_DIM) {
        float l2 = bl2[t];
        const float* wr = Wl2 + (size_t)t * 128;
        for (int kk = 0; kk < 128; ++kk) l2 += wr[kk] * s_x[kk];
        s_c[t] = l2;
    }
    __syncthreads();
    if (t < C_DIM) {
        float mx = -1e30f;
        for (int c = 0; c < C_DIM; ++c) mx = fmaxf(mx, s_c[c]);
        float se = 0.f;
        for (int c = 0; c < C_DIM; ++c) se += expf(s_c[c] - mx);
        out[(size_t)b * C_DIM + t] = expf(s_c[t] - mx) / se;
    }
}

// ---------------------------------------------------------------------------
// Launch
// ---------------------------------------------------------------------------
extern "C" void kernel_launch(void* const* d_in, const int* in_sizes, int n_in,
                              void* d_out, int out_size, void* d_ws, size_t ws_size,
                              hipStream_t stream) {
    const int*   nodes = (const int*)  d_in[0];
    const float* adj   = (const float*)d_in[1];
    const float* data  = (const float*)d_in[2];
    const float* W1    = (const float*)d_in[3];
    const float* b1    = (const float*)d_in[4];
    const float* W2    = (const float*)d_in[5];
    const float* b2    = (const float*)d_in[6];
    const float* Wl1   = (const float*)d_in[7];
    const float* bl1   = (const float*)d_in[8];
    const float* Wl2   = (const float*)d_in[9];
    const float* bl2   = (const float*)d_in[10];
    float* out = (float*)d_out;

    // workspace layout (all 16B-aligned)
    unsigned short* Wt1 = (unsigned short*)d_ws;            // 256*512 bf16
    unsigned short* Wt2 = Wt1 + 256 * KP1;                  // 256*128
    unsigned short* H1b = Wt2 + 256 * 128;                  // 16384*128
    float* Wl1t = (float*)(H1b + (size_t)N_NODES * 128);    // 128*128
    float* X    = Wl1t + 128 * 128;                         // 16384*256
    float* Y    = X    + (size_t)N_NODES * 256;             // 16384*256
    unsigned short* nbr = (unsigned short*)(Y + (size_t)N_NODES * 256); // 16384*128
    int*   deg  = (int*)(nbr + (size_t)N_NODES * MAXDEG);   // 16384

    // merged weight prep
    k_prep<<<656, 256, 0, stream>>>(W1, W2, Wl1, Wt1, Wt2, Wl1t);

    // GEMM1 + adj scan co-scheduled (independent), then gather+norm
    k_mix   <<<512 + N_NODES, 256, 0, stream>>>(data, Wt1, X, adj, nbr, deg);
    k_gather<<<N_NODES, 256, 0, stream>>>(nbr, deg, X, b1, H1b);

    // layer 2: MFMA GEMM on all nodes, then fused agg+norm+head per batch node
    k_gemm_mfma<<<N_NODES / 32, 256, 0, stream>>>(H1b, E_DIM, Wt2, Y);
    k_l2head   <<<B_DIM, 256, 0, stream>>>(nodes, nbr, deg, Y, b2, Wl1t, bl1, Wl2, bl2, out);
}